// Round 1
// baseline (260.541 us; speedup 1.0000x reference)
//
#include <hip/hip_runtime.h>

// Y = X @ H, H = normalized 4096x4096 Sylvester-Hadamard (symmetric).
// = per-row FWHT * 2^-6. Memory-bound: ~200-270 MB HBM traffic -> ~32-42 us
// floor at 6.3 TB/s.
//
// V3 (253 us bench / 80.8 us dispatch) counters: VALU 12.7%, HBM 31%, occupancy
// 64.5%, conflicts negligible -> latency-bound. Block lifetime ~20 us for ~2 us
// of work: one row per block is a single dependent chain (cold HBM load ->
// 3 phases with 2 FULL-DRAIN barriers -> store); __syncthreads emits
// s_waitcnt vmcnt(0) lgkmcnt(0), so nothing ever overlaps the drains.
//
// V4: 4 rows/block (grid 2048 = still 8 blocks/CU resident), depth-1 register
// prefetch of the next row issued BEFORE the current row's barriers, and raw
// s_barrier + lgkmcnt(0)-only waits (no vmcnt drain) so the prefetch stays in
// flight across all barriers. LDS exchange layout unchanged (<=3-way banked).
//
// Structure per row: one 256-thread block, 16 elements/thread.
//   Phase A: i = 16*t + k                  -> butterflies on k  (strides 1..8)
//   Phase B: i = a + 16*b + 256*c (t=a+16c)-> butterflies on b  (16..128)
//   Phase C: i = a + 16*b2 + 256*cc        -> butterflies on cc (256..2048)
// LDS padded addr(i) = i + (i>>4).

#define N12 4096
#define TPB 256
#define RPB 4   // rows per block; grid = 8192/4 = 2048 = exactly 8 blocks/CU

#define BF(p, q) do { float _u = (p), _w = (q); (p) = _u + _w; (q) = _u - _w; } while (0)

// 4 butterfly stages (local strides 1,2,4,8) over the 16 named scalars.
#define BFLY16()  do { \
    BF(v0,v1);  BF(v2,v3);  BF(v4,v5);   BF(v6,v7);   BF(v8,v9);  BF(v10,v11); BF(v12,v13); BF(v14,v15); \
    BF(v0,v2);  BF(v1,v3);  BF(v4,v6);   BF(v5,v7);   BF(v8,v10); BF(v9,v11);  BF(v12,v14); BF(v13,v15); \
    BF(v0,v4);  BF(v1,v5);  BF(v2,v6);   BF(v3,v7);   BF(v8,v12); BF(v9,v13);  BF(v10,v14); BF(v11,v15); \
    BF(v0,v8);  BF(v1,v9);  BF(v2,v10);  BF(v3,v11);  BF(v4,v12); BF(v5,v13);  BF(v6,v14);  BF(v7,v15); \
} while (0)

// Raw barrier: guarantees LDS visibility only (s_waitcnt lgkmcnt(0)).
// Deliberately NO vmcnt drain -- the next-row global prefetch must stay in
// flight across it. __syncthreads() would emit s_waitcnt vmcnt(0) and
// serialize the pipeline. "memory" clobbers pin all LDS/global ops on their
// side of the barrier.
#define BAR() do { \
    asm volatile("s_waitcnt lgkmcnt(0)" ::: "memory"); \
    __builtin_amdgcn_s_barrier(); \
    asm volatile("" ::: "memory"); \
} while (0)

__global__ __launch_bounds__(TPB) void fwht4096_pipe(const float* __restrict__ X,
                                                     float* __restrict__ Y) {
    __shared__ float lds[N12 + (N12 >> 4)];  // 4352 floats = 17 KB

    const int t = threadIdx.x;
    const long long row0 = (long long)blockIdx.x * RPB;
    const float4* __restrict__ x4 = (const float4*)(X + row0 * N12) + (t << 2);
    float* __restrict__ y = Y + row0 * N12;

    const int a = t & 15;
    const int c = t >> 4;
    float* const wA = lds + 17 * t;        // phase A->B write base (2-way banked)
    float* const pB = lds + a + 272 * c;   // phase B read/write-back base
    const float* const pC = lds + a + 17 * c;  // phase C read base

    // Prologue: issue row 0's loads (cold start -- paid once per block).
    float4 p0 = x4[0], p1 = x4[1], p2 = x4[2], p3 = x4[3];

#pragma unroll
    for (int k = 0; k < RPB; ++k) {
        // Unpack prefetched row into working registers.
        float v0  = p0.x, v1  = p0.y, v2  = p0.z, v3  = p0.w;
        float v4  = p1.x, v5  = p1.y, v6  = p1.z, v7  = p1.w;
        float v8  = p2.x, v9  = p2.y, v10 = p2.z, v11 = p2.w;
        float v12 = p3.x, v13 = p3.y, v14 = p3.z, v15 = p3.w;

        // Issue next row's loads NOW; results not needed until next iteration.
        // They ride through all three barriers below (no vmcnt drain).
        if (k + 1 < RPB) {
            const float4* xn = x4 + (size_t)(k + 1) * (N12 / 4);
            p0 = xn[0]; p1 = xn[1]; p2 = xn[2]; p3 = xn[3];
        }

        BFLY16();  // global strides 1,2,4,8

        // Prior row's phase-C reads must be complete before overwriting LDS.
        if (k) BAR();

        // ---- Exchange A->B: write addr = 17*t + j (2-way banked, free)
        wA[0]=v0;  wA[1]=v1;  wA[2]=v2;   wA[3]=v3;
        wA[4]=v4;  wA[5]=v5;  wA[6]=v6;   wA[7]=v7;
        wA[8]=v8;  wA[9]=v9;  wA[10]=v10; wA[11]=v11;
        wA[12]=v12; wA[13]=v13; wA[14]=v14; wA[15]=v15;
        BAR();

        // ---- Phase B: t = a + 16*c holds i = a + 16*b + 256*c; addr = a + 17*b + 272*c
        v0 = pB[0];    v1 = pB[17];   v2  = pB[34];  v3  = pB[51];
        v4 = pB[68];   v5 = pB[85];   v6  = pB[102]; v7  = pB[119];
        v8 = pB[136];  v9 = pB[153];  v10 = pB[170]; v11 = pB[187];
        v12 = pB[204]; v13 = pB[221]; v14 = pB[238]; v15 = pB[255];
        BFLY16();  // global strides 16,32,64,128

        // ---- Exchange B->C: overwrite exactly the addresses just read
        // (disjoint per-thread sets) -> no barrier before these writes.
        pB[0]=v0;    pB[17]=v1;   pB[34]=v2;   pB[51]=v3;
        pB[68]=v4;   pB[85]=v5;   pB[102]=v6;  pB[119]=v7;
        pB[136]=v8;  pB[153]=v9;  pB[170]=v10; pB[187]=v11;
        pB[204]=v12; pB[221]=v13; pB[238]=v14; pB[255]=v15;
        BAR();

        // ---- Phase C: addr = a + 17*b2 + 272*cc
        v0 = pC[0];      v1 = pC[272];    v2  = pC[544];   v3  = pC[816];
        v4 = pC[1088];   v5 = pC[1360];   v6  = pC[1632];  v7  = pC[1904];
        v8 = pC[2176];   v9 = pC[2448];   v10 = pC[2720];  v11 = pC[2992];
        v12 = pC[3264];  v13 = pC[3536];  v14 = pC[3808];  v15 = pC[4080];
        BFLY16();  // global strides 256,512,1024,2048

        // ---- Store: y[t + 256*cc] -> each wave store = 256 B contiguous
        const float s = 0.015625f;  // 2^-6
        float* __restrict__ yk = y + (size_t)k * N12;
        yk[t]        = v0  * s;  yk[t + 256]  = v1  * s;  yk[t + 512]  = v2  * s;  yk[t + 768]  = v3  * s;
        yk[t + 1024] = v4  * s;  yk[t + 1280] = v5  * s;  yk[t + 1536] = v6  * s;  yk[t + 1792] = v7  * s;
        yk[t + 2048] = v8  * s;  yk[t + 2304] = v9  * s;  yk[t + 2560] = v10 * s;  yk[t + 2816] = v11 * s;
        yk[t + 3072] = v12 * s;  yk[t + 3328] = v13 * s;  yk[t + 3584] = v14 * s;  yk[t + 3840] = v15 * s;
    }
}

extern "C" void kernel_launch(void* const* d_in, const int* in_sizes, int n_in,
                              void* d_out, int out_size, void* d_ws, size_t ws_size,
                              hipStream_t stream) {
    const float* X = (const float*)d_in[0];   // (ROWS, 4096) fp32
    // d_in[1] (dense H) unused: FWHT computed directly.
    float* Y = (float*)d_out;
    const int rows = in_sizes[0] / (N12 * 4) > 0 ? in_sizes[0] / N12 : 0; // in_sizes in elements
    // in_sizes[0] is the element count of X (ROWS*4096).
    const int nrows = in_sizes[0] / N12;      // 8192
    hipLaunchKernelGGL(fwht4096_pipe, dim3(nrows / RPB), dim3(TPB), 0, stream, X, Y);
    (void)rows;
}

// Round 2
// 259.837 us; speedup vs baseline: 1.0027x; 1.0027x over previous
//
#include <hip/hip_runtime.h>

// Y = X @ H, H = normalized 4096x4096 Sylvester-Hadamard = per-row FWHT * 2^-6.
// HBM floor: ~134 MB read + 134 MB write -> ~42 us at 6.3 TB/s.
//
// V3/V4 post-mortem: 81 us invariant across barrier-drain vs prefetch versions;
// VALU 12-13%, HBM 31%, LDS-pipe ~25% -- the pipes are SERIALIZED (sum ~= 81 us),
// not overlapped (max ~= 32 us). Cause: block-lockstep load->barrier->LDS->
// barrier->store structure; only 8 blocks/CU (17 KB LDS each) to decorrelate.
//
// V5: one WAVE per row, zero LDS, zero barriers. Lane l, reg m holds
// x[256m + 4l + e] (16 float4 = 64 floats/lane = full row across 64 lanes).
// FWHT stage per index bit:
//   bits 0-1 (e):  in-float4 adds (VALU)
//   bit 2 (lane^1):  DPP quad_perm [1,0,3,2] = 0xB1 (VALU pipe)
//   bit 3 (lane^2):  DPP quad_perm [2,3,0,1] = 0x4E (VALU pipe)
//   bit 4 (lane^4):  ds_swizzle xor4  = 0x101F (LDS pipe, no alloc, no barrier)
//   bit 5 (lane^8):  ds_swizzle xor8  = 0x201F
//   bit 6 (lane^16): ds_swizzle xor16 = 0x401F
//   bit 7 (lane^32): ds_bpermute addr=(l^32)<<2 (full-wave pull)
//   bits 8-11 (m): in-register butterflies across the 16 float4s
// Cross-lane butterfly: v' = s*v + partner, s = +-1 per lane bit -> 1 fma.
// Loads/stores: 16x global_{load,store}_dwordx4, 1 KB/instr contiguous/wave.
// Waves fully independent -> memory stream never drains; LDS-pipe work overlaps
// the HBM stream instead of being barrier-serialized against it.

#define TPB 256
#define RPB 4   // 4 waves/block, one row per wave

#define BF(p, q) do { float _u = (p), _w = (q); (p) = _u + _w; (q) = _u - _w; } while (0)

#define DPPX(x, ctrl) __int_as_float(__builtin_amdgcn_update_dpp(0, __float_as_int(x), (ctrl), 0xF, 0xF, false))
#define SWZ(x, imm)   __int_as_float(__builtin_amdgcn_ds_swizzle(__float_as_int(x), (imm)))
#define BPERM(x)      __int_as_float(__builtin_amdgcn_ds_bpermute(bp32, __float_as_int(x)))

// 6 cross-lane butterfly stages on one scalar (index bits 2..7 == lane bits 0..5)
#define LANE_STAGES(a) do { \
    float _w; \
    _w = DPPX((a), 0xB1);  (a) = fmaf(s0, (a), _w); \
    _w = DPPX((a), 0x4E);  (a) = fmaf(s1, (a), _w); \
    _w = SWZ((a), 0x101F); (a) = fmaf(s2, (a), _w); \
    _w = SWZ((a), 0x201F); (a) = fmaf(s3, (a), _w); \
    _w = SWZ((a), 0x401F); (a) = fmaf(s4, (a), _w); \
    _w = BPERM((a));       (a) = fmaf(s5, (a), _w); \
} while (0)

__global__ __launch_bounds__(TPB, 4) void fwht4096_lane(const float4* __restrict__ X4,
                                                        float4* __restrict__ Y4) {
    const int t = threadIdx.x;
    const int l = t & 63;
    const long long row = (long long)blockIdx.x * RPB + (t >> 6);
    const float4* __restrict__ x = X4 + row * 1024 + l;
    float4*       __restrict__ y = Y4 + row * 1024 + l;

    // Per-lane butterfly signs: bit clear -> +1 (u+w), bit set -> -1 (w-u).
    const float s0 = (l & 1)  ? -1.f : 1.f;
    const float s1 = (l & 2)  ? -1.f : 1.f;
    const float s2 = (l & 4)  ? -1.f : 1.f;
    const float s3 = (l & 8)  ? -1.f : 1.f;
    const float s4 = (l & 16) ? -1.f : 1.f;
    const float s5 = (l & 32) ? -1.f : 1.f;
    const int bp32 = (l ^ 32) << 2;   // ds_bpermute byte address

    float4 f[16];
#pragma unroll
    for (int m = 0; m < 16; ++m) f[m] = x[m * 64];

    // Per-chunk stages (bits 0-7): each float4 processed as soon as it lands,
    // so compute overlaps the tail of the load burst.
#pragma unroll
    for (int m = 0; m < 16; ++m) {
        float a = f[m].x, b = f[m].y, c = f[m].z, d = f[m].w;
        BF(a, b); BF(c, d);   // bit 0
        BF(a, c); BF(b, d);   // bit 1
        LANE_STAGES(a); LANE_STAGES(b); LANE_STAGES(c); LANE_STAGES(d);
        f[m].x = a; f[m].y = b; f[m].z = c; f[m].w = d;
    }

    // Bits 8-11: in-lane butterflies across the 16 float4 registers.
#pragma unroll
    for (int s = 1; s < 16; s <<= 1) {
#pragma unroll
        for (int m = 0; m < 16; ++m) {
            if (!(m & s)) {
                BF(f[m].x, f[m | s].x);
                BF(f[m].y, f[m | s].y);
                BF(f[m].z, f[m | s].z);
                BF(f[m].w, f[m | s].w);
            }
        }
    }

    const float sc = 0.015625f;  // 2^-6 normalization
#pragma unroll
    for (int m = 0; m < 16; ++m) {
        float4 o;
        o.x = f[m].x * sc; o.y = f[m].y * sc; o.z = f[m].z * sc; o.w = f[m].w * sc;
        y[m * 64] = o;
    }
}

extern "C" void kernel_launch(void* const* d_in, const int* in_sizes, int n_in,
                              void* d_out, int out_size, void* d_ws, size_t ws_size,
                              hipStream_t stream) {
    const float* X = (const float*)d_in[0];   // (ROWS, 4096) fp32
    // d_in[1] (dense H) unused: FWHT computed directly.
    float* Y = (float*)d_out;
    const int nrows = in_sizes[0] / 4096;     // 8192
    hipLaunchKernelGGL(fwht4096_lane, dim3(nrows / RPB), dim3(TPB), 0, stream,
                       (const float4*)X, (float4*)Y);
}

// Round 5
// 255.644 us; speedup vs baseline: 1.0192x; 1.0164x over previous
//
#include <hip/hip_runtime.h>

// Y = X @ H, H = normalized 4096x4096 Sylvester-Hadamard = per-row FWHT * 2^-6.
// HBM floor ~32-42 us at 6.3 TB/s (~64-128 MB read + 128 MB write).
//
// History: V3 (LDS+barriers) 81us, V4 (prefetch, lgkm-only bars) 83us,
// V5 (pure cross-lane, 1 row/wave) 84us, V6 (permlane swaps) WRONG RESULTS,
// V7 compile error (__builtin_nontemporal_store rejects HIP_vector_type
// float4 -- needs a clang ext_vector_type pointer; fixed here).
//
// Counters across V3-V5: all pipes idle (VALU 11-13%, LDS ~25%, HBM ~30%),
// occupancy ~31% -> latency-bound. V5 root causes: (a) compiler clamped to
// VGPR=64 chasing occupancy -> 16 chunks processed serially, each a 4-deep
// ds_swizzle latency chain (~4800 stalled cy/row); (b) one-shot grid: all
// waves load in one synchronized burst (massive queueing), and each wave's
// loads/stores never overlap -> memory stream never steady.
//
// V7b: V5's VERIFIED exchange ladder (DPP quad_perm 0xB1/0x4E, ds_swizzle
// xor4/8/16, ds_bpermute xor32 -- passed twice on HW). Structural changes:
//  - persistent waves: TPB=64 (1 wave/block), grid 2048, 4 rows/wave,
//    register double-buffer: row k+1 loads in flight under row k compute,
//    row k stores issued right after -> continuous mixed read+write stream.
//  - __launch_bounds__(64,2): VGPR cap 256 so the ~160-reg double buffer is
//    NOT compressed to 64 (what defeated V4/V5 prefetching).
//  - non-temporal stores for Y: no write-allocate -> Y stops evicting X from
//    L3 (X is partially L3-resident: FETCH was 64MB of 128MB input).
//
// Layout per row: lane l, reg m holds x[256m + 4l + e]; stages per index bit:
//   bits 0-1: in-float4 adds | bit2: DPP 0xB1 | bit3: DPP 0x4E
//   bit4: swz xor4 0x101F | bit5: swz xor8 0x201F | bit6: swz xor16 0x401F
//   bit7: ds_bpermute (l^32) | bits 8-11: cross-register adds.

#define TPB 64
#define RPW 4   // rows per wave; grid = 8192/4 = 2048 blocks (8 waves/CU)

typedef float floatx4 __attribute__((ext_vector_type(4)));  // native vec for NT store

#define BF(p, q) do { float _u = (p), _w = (q); (p) = _u + _w; (q) = _u - _w; } while (0)

#define DPPX(x, ctrl) __int_as_float(__builtin_amdgcn_update_dpp(0, __float_as_int(x), (ctrl), 0xF, 0xF, false))
#define SWZ(x, imm)   __int_as_float(__builtin_amdgcn_ds_swizzle(__float_as_int(x), (imm)))
#define BPERM(x)      __int_as_float(__builtin_amdgcn_ds_bpermute(bp32, __float_as_int(x)))

// Cross-lane ladder on one scalar (index bits 2..7 == lane bits 0..5).
// Butterfly: out = s*self + partner (s=+1 lane-bit clear, -1 set).
#define LANE_STAGES(a) do { \
    float _w; \
    _w = DPPX((a), 0xB1);   (a) = fmaf(s0, (a), _w);  /* xor1  */ \
    _w = DPPX((a), 0x4E);   (a) = fmaf(s1, (a), _w);  /* xor2  */ \
    _w = SWZ((a), 0x101F);  (a) = fmaf(s2, (a), _w);  /* xor4  */ \
    _w = SWZ((a), 0x201F);  (a) = fmaf(s3, (a), _w);  /* xor8  */ \
    _w = SWZ((a), 0x401F);  (a) = fmaf(s4, (a), _w);  /* xor16 */ \
    _w = BPERM((a));        (a) = fmaf(s5, (a), _w);  /* xor32 */ \
} while (0)

#define LOADR(f, p) do { _Pragma("unroll") \
    for (int m = 0; m < 16; ++m) (f)[m] = (p)[m * 64]; } while (0)

#define COMPUTE(f) do { \
    _Pragma("unroll") \
    for (int m = 0; m < 16; ++m) { \
        float a = (f)[m].x, b = (f)[m].y, c = (f)[m].z, d = (f)[m].w; \
        BF(a, b); BF(c, d);   /* bit 0 */ \
        BF(a, c); BF(b, d);   /* bit 1 */ \
        LANE_STAGES(a); LANE_STAGES(b); LANE_STAGES(c); LANE_STAGES(d); \
        (f)[m].x = a; (f)[m].y = b; (f)[m].z = c; (f)[m].w = d; \
    } \
    _Pragma("unroll") \
    for (int s = 1; s < 16; s <<= 1) { \
        _Pragma("unroll") \
        for (int m = 0; m < 16; ++m) { \
            if (!(m & s)) { \
                BF((f)[m].x, (f)[m | s].x); BF((f)[m].y, (f)[m | s].y); \
                BF((f)[m].z, (f)[m | s].z); BF((f)[m].w, (f)[m | s].w); \
            } \
        } \
    } \
} while (0)

// Scale 2^-6 folded into the (non-temporal) store.
#define STORER(f, p) do { _Pragma("unroll") \
    for (int m = 0; m < 16; ++m) { \
        floatx4 _o; \
        _o.x = (f)[m].x * 0.015625f; _o.y = (f)[m].y * 0.015625f; \
        _o.z = (f)[m].z * 0.015625f; _o.w = (f)[m].w * 0.015625f; \
        __builtin_nontemporal_store(_o, (floatx4*)&(p)[m * 64]); \
    } } while (0)

__global__ __launch_bounds__(TPB, 2) void fwht4096_v7(const float4* __restrict__ X4,
                                                      float4* __restrict__ Y4) {
    const int l = threadIdx.x;   // lane 0..63; one wave per block

    const float s0 = (l & 1)  ? -1.f : 1.f;
    const float s1 = (l & 2)  ? -1.f : 1.f;
    const float s2 = (l & 4)  ? -1.f : 1.f;
    const float s3 = (l & 8)  ? -1.f : 1.f;
    const float s4 = (l & 16) ? -1.f : 1.f;
    const float s5 = (l & 32) ? -1.f : 1.f;
    const int bp32 = (l ^ 32) << 2;   // ds_bpermute byte address

    // Rows strided by gridDim.x: at any instant the grid works a contiguous
    // 2048-row (32 MB) window -> good L2/L3 behavior.
    const long long S4 = (long long)gridDim.x * 1024;   // row stride in float4
    long long off = (long long)blockIdx.x * 1024 + l;

    float4 fA[16], fB[16];   // double buffer: ~128 VGPR of row data

    LOADR(fA, X4 + off);     // prologue: row r0 in flight

#pragma unroll 1
    for (int g = 0; g < RPW; g += 2) {
        LOADR(fB, X4 + off + S4);            // next row under current compute
        COMPUTE(fA);
        STORER(fA, Y4 + off);
        if (g + 2 < RPW) LOADR(fA, X4 + off + 2 * S4);
        COMPUTE(fB);                          // fA's loads in flight here
        STORER(fB, Y4 + off + S4);
        off += 2 * S4;
    }
}

extern "C" void kernel_launch(void* const* d_in, const int* in_sizes, int n_in,
                              void* d_out, int out_size, void* d_ws, size_t ws_size,
                              hipStream_t stream) {
    const float* X = (const float*)d_in[0];   // (ROWS, 4096) fp32
    // d_in[1] (dense H) unused: FWHT computed directly.
    float* Y = (float*)d_out;
    const int nrows = in_sizes[0] / 4096;     // 8192
    hipLaunchKernelGGL(fwht4096_v7, dim3(nrows / RPW), dim3(TPB), 0, stream,
                       (const float4*)X, (float4*)Y);
}

// Round 6
// 255.553 us; speedup vs baseline: 1.0195x; 1.0004x over previous
//
#include <hip/hip_runtime.h>

// Y = X @ H, H = normalized 4096x4096 Sylvester-Hadamard = per-row FWHT * 2^-6.
// HBM floor ~32-42 us at 6.3 TB/s.
//
// History: V3 (LDS+barriers, 32 waves/CU) 80us; V4 (prefetch+lgkm-bars) 83us;
// V5 (pure cross-lane) 84us; V7b (reg double-buffer + NT stores, 8 waves/CU)
// 80us. INVARIANT: ~2.5 us/row/CU (~12.8 GB/s/CU) across 4x occupancy range
// and all structures. Key defect found each time: compiler's pressure-
// minimizing scheduler collapsed every double buffer (VGPR 32/64/108 vs the
// ~160 needed) -> loads never actually in flight under compute -> every wave
// alternates load-burst/compute in phase -> HBM and ALUs take turns at the
// device level (20us read + ~10 VALU + ~20 LDS + 20 write serial ~= 80us).
//
// V8: V7b verbatim (exchange ladder verified on HW twice) plus
// __attribute__((amdgpu_waves_per_eu(2,2))): max=2 waves/EU makes the
// backend TARGET 256 VGPR pressure, so fA/fB (128 VGPR) survive regalloc and
// the next-row load burst truly overlaps current-row compute.
// Discriminates: if dur drops (45-60us) -> phase-lock theory right;
// if flat at ~80 with VGPR>=160 -> per-CU memory-concurrency cap, attack
// cache path next.
//
// Layout per row: lane l, reg m holds x[256m + 4l + e]; stages per index bit:
//   bits 0-1: in-float4 adds | bit2: DPP 0xB1 | bit3: DPP 0x4E
//   bit4: swz xor4 0x101F | bit5: swz xor8 0x201F | bit6: swz xor16 0x401F
//   bit7: ds_bpermute (l^32) | bits 8-11: cross-register adds.

#define TPB 64
#define RPW 4   // rows per wave; grid = 8192/4 = 2048 blocks (8 waves/CU)

typedef float floatx4 __attribute__((ext_vector_type(4)));  // native vec for NT store

#define BF(p, q) do { float _u = (p), _w = (q); (p) = _u + _w; (q) = _u - _w; } while (0)

#define DPPX(x, ctrl) __int_as_float(__builtin_amdgcn_update_dpp(0, __float_as_int(x), (ctrl), 0xF, 0xF, false))
#define SWZ(x, imm)   __int_as_float(__builtin_amdgcn_ds_swizzle(__float_as_int(x), (imm)))
#define BPERM(x)      __int_as_float(__builtin_amdgcn_ds_bpermute(bp32, __float_as_int(x)))

// Cross-lane ladder on one scalar (index bits 2..7 == lane bits 0..5).
// Butterfly: out = s*self + partner (s=+1 lane-bit clear, -1 set).
#define LANE_STAGES(a) do { \
    float _w; \
    _w = DPPX((a), 0xB1);   (a) = fmaf(s0, (a), _w);  /* xor1  */ \
    _w = DPPX((a), 0x4E);   (a) = fmaf(s1, (a), _w);  /* xor2  */ \
    _w = SWZ((a), 0x101F);  (a) = fmaf(s2, (a), _w);  /* xor4  */ \
    _w = SWZ((a), 0x201F);  (a) = fmaf(s3, (a), _w);  /* xor8  */ \
    _w = SWZ((a), 0x401F);  (a) = fmaf(s4, (a), _w);  /* xor16 */ \
    _w = BPERM((a));        (a) = fmaf(s5, (a), _w);  /* xor32 */ \
} while (0)

#define LOADR(f, p) do { _Pragma("unroll") \
    for (int m = 0; m < 16; ++m) (f)[m] = (p)[m * 64]; } while (0)

#define COMPUTE(f) do { \
    _Pragma("unroll") \
    for (int m = 0; m < 16; ++m) { \
        float a = (f)[m].x, b = (f)[m].y, c = (f)[m].z, d = (f)[m].w; \
        BF(a, b); BF(c, d);   /* bit 0 */ \
        BF(a, c); BF(b, d);   /* bit 1 */ \
        LANE_STAGES(a); LANE_STAGES(b); LANE_STAGES(c); LANE_STAGES(d); \
        (f)[m].x = a; (f)[m].y = b; (f)[m].z = c; (f)[m].w = d; \
    } \
    _Pragma("unroll") \
    for (int s = 1; s < 16; s <<= 1) { \
        _Pragma("unroll") \
        for (int m = 0; m < 16; ++m) { \
            if (!(m & s)) { \
                BF((f)[m].x, (f)[m | s].x); BF((f)[m].y, (f)[m | s].y); \
                BF((f)[m].z, (f)[m | s].z); BF((f)[m].w, (f)[m | s].w); \
            } \
        } \
    } \
} while (0)

// Scale 2^-6 folded into the (non-temporal) store.
#define STORER(f, p) do { _Pragma("unroll") \
    for (int m = 0; m < 16; ++m) { \
        floatx4 _o; \
        _o.x = (f)[m].x * 0.015625f; _o.y = (f)[m].y * 0.015625f; \
        _o.z = (f)[m].z * 0.015625f; _o.w = (f)[m].w * 0.015625f; \
        __builtin_nontemporal_store(_o, (floatx4*)&(p)[m * 64]); \
    } } while (0)

__global__ __launch_bounds__(TPB)
__attribute__((amdgpu_waves_per_eu(2, 2)))
void fwht4096_v8(const float4* __restrict__ X4, float4* __restrict__ Y4) {
    const int l = threadIdx.x;   // lane 0..63; one wave per block

    const float s0 = (l & 1)  ? -1.f : 1.f;
    const float s1 = (l & 2)  ? -1.f : 1.f;
    const float s2 = (l & 4)  ? -1.f : 1.f;
    const float s3 = (l & 8)  ? -1.f : 1.f;
    const float s4 = (l & 16) ? -1.f : 1.f;
    const float s5 = (l & 32) ? -1.f : 1.f;
    const int bp32 = (l ^ 32) << 2;   // ds_bpermute byte address

    // Rows strided by gridDim.x: at any instant the grid works a contiguous
    // 2048-row (32 MB) window -> good L2/L3 behavior.
    const long long S4 = (long long)gridDim.x * 1024;   // row stride in float4
    long long off = (long long)blockIdx.x * 1024 + l;

    float4 fA[16], fB[16];   // double buffer: 128 VGPR of row data

    LOADR(fA, X4 + off);     // prologue: row r0 in flight

#pragma unroll 1
    for (int g = 0; g < RPW; g += 2) {
        LOADR(fB, X4 + off + S4);            // next row under current compute
        COMPUTE(fA);
        STORER(fA, Y4 + off);
        if (g + 2 < RPW) LOADR(fA, X4 + off + 2 * S4);
        COMPUTE(fB);                          // fA's loads in flight here
        STORER(fB, Y4 + off + S4);
        off += 2 * S4;
    }
}

extern "C" void kernel_launch(void* const* d_in, const int* in_sizes, int n_in,
                              void* d_out, int out_size, void* d_ws, size_t ws_size,
                              hipStream_t stream) {
    const float* X = (const float*)d_in[0];   // (ROWS, 4096) fp32
    // d_in[1] (dense H) unused: FWHT computed directly.
    float* Y = (float*)d_out;
    const int nrows = in_sizes[0] / 4096;     // 8192
    hipLaunchKernelGGL(fwht4096_v8, dim3(nrows / RPW), dim3(TPB), 0, stream,
                       (const float4*)X, (float4*)Y);
}